// Round 5
// baseline (211.256 us; speedup 1.0000x reference)
//
#include <hip/hip_runtime.h>

// SGE-style gate: B=64, C=512, HW=784, G=8, cpg=64.
//
// R4 post-mortem: single-kernel register-resident version is PHASE-SERIALIZED:
// 512 blocks = exactly 2/CU, no backfill; all blocks do [read 196KB, stall
// vmcnt(0)] -> compute -> [write 196KB] in chip-wide lockstep. Read and write
// bursts never overlap -> 67us at 2.3TB/s with VALUBusy 6%. Pin was neutral
// (compiler already kept tile in AGPRs; FETCH/WRITE already single-pass).
//
// Fix: 2-kernel split.
//  K1: 1024 blocks x 512 thr, each = half tile (32ch x 784). Per-channel means
//      are block-local; writes partial s (784 floats) to ws. 2x oversubscribed
//      -> backfill staggers the read bursts. Negligible writes.
//  K2: 512 blocks x 1024 thr: s = wsA+wsB, mu/var/gate -> LDS, then pure
//      streaming apply (x4 load/mul/store interleaved, compiler-pipelined).
//      x is L3-resident (102MB < 256MB) after K1.

#define HW    784
#define HW4   196
#define K4    12
#define NG    8

__global__ __launch_bounds__(512, 4)
void sge_partial_s(const float* __restrict__ x, float* __restrict__ ws) {
    __shared__ float sbuf[8 * HW];    // per-wave 4-channel partials of s

    const int t    = threadIdx.x;
    const int c    = t >> 4;          // 0..31 channel within half-tile
    const int j    = t & 15;
    const int wave = t >> 6;          // 0..7
    const int lane = t & 63;

    const int bg   = blockIdx.x >> 1;
    const int half = blockIdx.x & 1;
    const size_t base4 = (size_t)bg * (64 * HW4) + (size_t)half * (32 * HW4)
                       + (size_t)c * HW4;

    const float4* xp = (const float4*)x + base4;
    float4 v[K4 + 1];
#pragma unroll
    for (int k = 0; k < K4; ++k) v[k] = xp[j + 16 * k];
    v[K4] = (j < 4) ? xp[192 + j] : make_float4(0.f, 0.f, 0.f, 0.f);

    // ---- per-channel spatial mean (16 lanes/channel, intra-wave) ----
    float cs = 0.f;
#pragma unroll
    for (int k = 0; k <= K4; ++k) cs += (v[k].x + v[k].y) + (v[k].z + v[k].w);
    cs += __shfl_xor(cs, 1, 64);
    cs += __shfl_xor(cs, 2, 64);
    cs += __shfl_xor(cs, 4, 64);
    cs += __shfl_xor(cs, 8, 64);
    const float mean_c = cs * (1.0f / (float)HW);

    // ---- partial s: sum of v*mean over the wave's 4 channels ----
    float4* srow = (float4*)(sbuf + wave * HW);
#pragma unroll
    for (int k = 0; k <= K4; ++k) {
        float4 w;
        w.x = v[k].x * mean_c; w.y = v[k].y * mean_c;
        w.z = v[k].z * mean_c; w.w = v[k].w * mean_c;
        w.x += __shfl_xor(w.x, 16, 64); w.x += __shfl_xor(w.x, 32, 64);
        w.y += __shfl_xor(w.y, 16, 64); w.y += __shfl_xor(w.y, 32, 64);
        w.z += __shfl_xor(w.z, 16, 64); w.z += __shfl_xor(w.z, 32, 64);
        w.w += __shfl_xor(w.w, 16, 64); w.w += __shfl_xor(w.w, 32, 64);
        if (k < K4) {
            if (lane < 16) srow[j + 16 * k] = w;
        } else {
            if (lane < 4) srow[192 + j] = w;   // lane==j<4
        }
    }
    __syncthreads();

    // ---- cross-wave sum over 8 rows; write partial s to ws ----
    float* wrow = ws + (size_t)blockIdx.x * HW;   // row index = bg*2+half
    {
        float s = 0.f;
#pragma unroll
        for (int w = 0; w < 8; ++w) s += sbuf[w * HW + t];
        wrow[t] = s;
    }
    if (t < HW - 512) {
        const int p = t + 512;
        float s = 0.f;
#pragma unroll
        for (int w = 0; w < 8; ++w) s += sbuf[w * HW + p];
        wrow[p] = s;
    }
}

__global__ __launch_bounds__(1024, 4)
void sge_apply(const float* __restrict__ x, const float* __restrict__ ws,
               const float* __restrict__ weight, const float* __restrict__ bias,
               float* __restrict__ out) {
    __shared__ float gate[HW];
    __shared__ float redbuf[32];

    const int t    = threadIdx.x;
    const int wave = t >> 6;
    const int lane = t & 63;
    const int bg   = blockIdx.x;
    const int g    = bg & (NG - 1);

    // ---- s = sum of the two half-tile partials ----
    float s = 0.f;
    if (t < HW) s = ws[(size_t)(2 * bg) * HW + t] + ws[(size_t)(2 * bg + 1) * HW + t];

    // ---- block reduction for mu, var ----
    float rs = s, rs2 = s * s;
#pragma unroll
    for (int m = 1; m < 64; m <<= 1) {
        rs  += __shfl_xor(rs,  m, 64);
        rs2 += __shfl_xor(rs2, m, 64);
    }
    if (lane == 0) { redbuf[wave] = rs; redbuf[16 + wave] = rs2; }
    __syncthreads();

    float sum_s = 0.f, sum_s2 = 0.f;
#pragma unroll
    for (int w = 0; w < 16; ++w) { sum_s += redbuf[w]; sum_s2 += redbuf[16 + w]; }
    const float mu   = sum_s * (1.0f / (float)HW);
    const float var  = sum_s2 * (1.0f / (float)HW) - mu * mu;
    const float rstd = rsqrtf(var + 1e-5f);

    if (t < HW) {
        const float z = (s - mu) * rstd * weight[g] + bias[g];
        gate[t] = 1.0f / (1.0f + __expf(-z));
    }
    __syncthreads();

    // ---- streaming apply: out = x * gate (no register residency) ----
    const int c = t >> 4;
    const int j = t & 15;
    const size_t base4 = (size_t)bg * (64 * HW4) + (size_t)c * HW4;
    const float4* xp = (const float4*)x + base4;
    float4* op = (float4*)out + base4;
    const float4* gate4 = (const float4*)gate;
#pragma unroll
    for (int k = 0; k < K4; ++k) {
        const float4 xv = xp[j + 16 * k];
        const float4 gv = gate4[j + 16 * k];
        float4 o;
        o.x = xv.x * gv.x; o.y = xv.y * gv.y;
        o.z = xv.z * gv.z; o.w = xv.w * gv.w;
        op[j + 16 * k] = o;
    }
    if (j < 4) {
        const float4 xv = xp[192 + j];
        const float4 gv = gate4[192 + j];
        float4 o;
        o.x = xv.x * gv.x; o.y = xv.y * gv.y;
        o.z = xv.z * gv.z; o.w = xv.w * gv.w;
        op[192 + j] = o;
    }
}

extern "C" void kernel_launch(void* const* d_in, const int* in_sizes, int n_in,
                              void* d_out, int out_size, void* d_ws, size_t ws_size,
                              hipStream_t stream) {
    const float* x      = (const float*)d_in[0];
    const float* weight = (const float*)d_in[1];
    const float* bias   = (const float*)d_in[2];
    float* out = (float*)d_out;
    float* ws  = (float*)d_ws;   // needs 1024*784*4 = 3.2 MB

    sge_partial_s<<<dim3(1024), dim3(512), 0, stream>>>(x, ws);
    sge_apply<<<dim3(512), dim3(1024), 0, stream>>>(x, ws, weight, bias, out);
}

// Round 7
// 202.333 us; speedup vs baseline: 1.0441x; 1.0441x over previous
//
#include <hip/hip_runtime.h>

// SGE-style gate: B=64, C=512, HW=784, G=8, cpg=64.  Fully-streaming 3-kernel
// split (R5 post-mortem: fused kernel is phase-serialized at 2 blocks/CU:
// read-burst + LDS-shuffle s-phase + write-burst in lockstep = 67us. Fix:
// copy-ubench-shaped kernels, 256-thr blocks, big grids).
// R6: __builtin_nontemporal_store needs a native clang vector type, not
// HIP's float4 struct -> ext_vector_type(4) alias for the K2 stream.
//
//  K1  (2048 blk x 256 thr): quarter-tile (16ch x 784). Channel means are
//      block-local; writes 16-channel partial s (784 f32) to ws. ~7 blk/CU.
//  K1.5 (512 blk x 256 thr): s = sum of 4 partials; mu/var/gate -> gbuf.
//  K2  (49x512 blk x 256 thr): out = x * gate. One x4 load + one L2-hit
//      gate4 load + mul + nontemporal store per thread. Textbook stream.

#define HW    784
#define HW4   196
#define K4    12
#define NG    8

typedef float v4f __attribute__((ext_vector_type(4)));

// ---------------- K1: per-quarter-tile partial s ----------------
__global__ __launch_bounds__(256, 4)
void sge_partial_s(const float* __restrict__ x, float* __restrict__ ws) {
    __shared__ float sbuf[4 * HW];    // 4 waves x 784 partial rows

    const int t    = threadIdx.x;
    const int c    = t >> 4;          // 0..15 channel within quarter
    const int j    = t & 15;
    const int wave = t >> 6;          // 0..3
    const int lane = t & 63;

    const int bx   = blockIdx.x;      // 0..2047
    const int tile = bx >> 2;
    const int q    = bx & 3;
    const size_t base4 = (size_t)tile * (64 * HW4) + (size_t)(q * 16 + c) * HW4;

    const float4* xp = (const float4*)x + base4;
    float4 v[K4 + 1];
#pragma unroll
    for (int k = 0; k < K4; ++k) v[k] = xp[j + 16 * k];
    v[K4] = (j < 4) ? xp[192 + j] : make_float4(0.f, 0.f, 0.f, 0.f);

    // per-channel spatial mean (16 lanes/channel)
    float cs = 0.f;
#pragma unroll
    for (int k = 0; k <= K4; ++k) cs += (v[k].x + v[k].y) + (v[k].z + v[k].w);
    cs += __shfl_xor(cs, 1, 64);
    cs += __shfl_xor(cs, 2, 64);
    cs += __shfl_xor(cs, 4, 64);
    cs += __shfl_xor(cs, 8, 64);
    const float mean_c = cs * (1.0f / (float)HW);

    // partial s over this wave's 4 channels
    float4* srow = (float4*)(sbuf + wave * HW);
#pragma unroll
    for (int k = 0; k <= K4; ++k) {
        float4 w;
        w.x = v[k].x * mean_c; w.y = v[k].y * mean_c;
        w.z = v[k].z * mean_c; w.w = v[k].w * mean_c;
        w.x += __shfl_xor(w.x, 16, 64); w.x += __shfl_xor(w.x, 32, 64);
        w.y += __shfl_xor(w.y, 16, 64); w.y += __shfl_xor(w.y, 32, 64);
        w.z += __shfl_xor(w.z, 16, 64); w.z += __shfl_xor(w.z, 32, 64);
        w.w += __shfl_xor(w.w, 16, 64); w.w += __shfl_xor(w.w, 32, 64);
        if (k < K4) {
            if (lane < 16) srow[j + 16 * k] = w;
        } else {
            if (lane < 4) srow[192 + j] = w;
        }
    }
    __syncthreads();

    // cross-wave sum (4 rows) -> ws[bx][p]
    float* wrow = ws + (size_t)bx * HW;
#pragma unroll
    for (int m = 0; m < 3; ++m) {
        const int p = t + 256 * m;
        float s = sbuf[p] + sbuf[HW + p] + sbuf[2 * HW + p] + sbuf[3 * HW + p];
        wrow[p] = s;
    }
    if (t < HW - 768) {
        const int p = t + 768;
        float s = sbuf[p] + sbuf[HW + p] + sbuf[2 * HW + p] + sbuf[3 * HW + p];
        wrow[p] = s;
    }
}

// ---------------- K1.5: reduce partials -> gate ----------------
__global__ __launch_bounds__(256, 4)
void sge_gate(const float* __restrict__ ws, const float* __restrict__ weight,
              const float* __restrict__ bias, float* __restrict__ gbuf) {
    __shared__ float redbuf[8];

    const int t    = threadIdx.x;
    const int wave = t >> 6;
    const int lane = t & 63;
    const int tile = blockIdx.x;
    const int g    = tile & (NG - 1);
    const float* wsA = ws + (size_t)(tile * 4) * HW;

    float sv[4];
    float rs = 0.f, rs2 = 0.f;
#pragma unroll
    for (int m = 0; m < 4; ++m) {
        const int p = t + 256 * m;
        float s = 0.f;
        if (m < 3 || t < HW - 768)
            s = wsA[p] + wsA[HW + p] + wsA[2 * HW + p] + wsA[3 * HW + p];
        sv[m] = s;
        rs += s; rs2 += s * s;
    }
#pragma unroll
    for (int m = 1; m < 64; m <<= 1) {
        rs  += __shfl_xor(rs,  m, 64);
        rs2 += __shfl_xor(rs2, m, 64);
    }
    if (lane == 0) { redbuf[wave] = rs; redbuf[4 + wave] = rs2; }
    __syncthreads();

    float sum_s = redbuf[0] + redbuf[1] + redbuf[2] + redbuf[3];
    float sum_s2 = redbuf[4] + redbuf[5] + redbuf[6] + redbuf[7];
    const float mu   = sum_s * (1.0f / (float)HW);
    const float var  = sum_s2 * (1.0f / (float)HW) - mu * mu;
    const float rstd = rsqrtf(var + 1e-5f);
    const float wg   = weight[g];
    const float bgv  = bias[g];

    float* grow = gbuf + (size_t)tile * HW;
#pragma unroll
    for (int m = 0; m < 4; ++m) {
        const int p = t + 256 * m;
        if (m < 3 || t < HW - 768) {
            const float z = (sv[m] - mu) * rstd * wg + bgv;
            grow[p] = 1.0f / (1.0f + __expf(-z));
        }
    }
}

// ---------------- K2: streaming apply ----------------
__global__ __launch_bounds__(256, 8)
void sge_apply(const float* __restrict__ x, const float* __restrict__ gbuf,
               float* __restrict__ out) {
    const int  t    = threadIdx.x;
    const int  tile = blockIdx.y;
    const int  i4   = blockIdx.x * 256 + t;       // 0..12543 float4 within tile
    const int  p4   = i4 % HW4;                   // float4 index within row

    const size_t idx = (size_t)tile * (64 * HW4) + i4;
    const v4f xv = __builtin_nontemporal_load(&((const v4f*)x)[idx]);
    const v4f gv = ((const v4f*)(gbuf + (size_t)tile * HW))[p4];
    const v4f o  = xv * gv;
    __builtin_nontemporal_store(o, &((v4f*)out)[idx]);
}

extern "C" void kernel_launch(void* const* d_in, const int* in_sizes, int n_in,
                              void* d_out, int out_size, void* d_ws, size_t ws_size,
                              hipStream_t stream) {
    const float* x      = (const float*)d_in[0];
    const float* weight = (const float*)d_in[1];
    const float* bias   = (const float*)d_in[2];
    float* out  = (float*)d_out;
    float* ws   = (float*)d_ws;                 // region A: 2048*784 f32 = 6.4MB
    float* gbuf = ws + (size_t)2048 * HW;       // region B: 512*784 f32 = 1.6MB

    sge_partial_s<<<dim3(2048), dim3(256), 0, stream>>>(x, ws);
    sge_gate<<<dim3(512), dim3(256), 0, stream>>>(ws, weight, bias, gbuf);
    sge_apply<<<dim3(49, 512), dim3(256), 0, stream>>>(x, gbuf, out);
}